// Round 7
// baseline (40753.329 us; speedup 1.0000x reference)
//
#include <hip/hip_runtime.h>
#include <math.h>

// Shapes:
// x:  [8, 2, 2048, 256]
// L1: conv k(8,1) s(4,1) p(2,0): -> [8,48,512,256]; gelu; 1x1 ->96; GLU -> [8,48,512,256]  (y1, ws)
// L2: conv -> [8,96,128,256]; gelu (g2, staged in d_out latent region); 1x1 ->192; GLU -> beforvq (d_out)
// VQ: argmin over 1024 codes of ||f - c||^2, latent = codebook[idx]
//
// d_out layout (fp32): latent [25165824] | indices-as-float [262144] | beforvq [25165824]

#define H1IN 2048
#define H1OUT 512
#define H2IN 512
#define H2OUT 128
#define TT 256
#define NPTS 32768           // 128*256 per batch
#define LAT_ELEMS 25165824   // 8*96*128*256
#define IDX_ELEMS 262144

// ---------------- prep: transpose weights, codebook norms ----------------
__global__ __launch_bounds__(256) void prep_kernel(
    const float* __restrict__ w1, const float* __restrict__ w2,
    const float* __restrict__ w3, const float* __restrict__ w4,
    const float* __restrict__ cb,
    float* __restrict__ w1t, float* __restrict__ w2t,
    float* __restrict__ w3t, float* __restrict__ w4t,
    float* __restrict__ cnorm)
{
    int i = blockIdx.x * 256 + threadIdx.x;
    if (i < 768) {                       // w1t[(ci*8+kh)*48+oc] = w1[(oc*2+ci)*8+kh]
        int oc = i % 48; int r = i / 48;
        w1t[i] = w1[(oc * 2 + (r >> 3)) * 8 + (r & 7)];
    } else if (i < 5376) {               // w2t[c*96+oc] = w2[oc*48+c]
        int j = i - 768;
        int oc = j % 96, c = j / 96;
        w2t[j] = w2[oc * 48 + c];
    } else if (i < 42240) {              // w3t[(ci*8+kh)*96+oc] = w3[(oc*48+ci)*8+kh]
        int j = i - 5376;
        int oc = j % 96; int r = j / 96;
        w3t[j] = w3[(oc * 48 + (r >> 3)) * 8 + (r & 7)];
    } else if (i < 60672) {              // w4t[c*192+oc] = w4[oc*96+c]
        int j = i - 42240;
        int oc = j % 192, c = j / 192;
        w4t[j] = w4[oc * 96 + c];
    } else if (i < 61696) {              // cnorm[k] = sum_d cb[k][d]^2 (fp64 accumulate)
        int k = i - 60672;
        const float* cp = cb + (size_t)k * 96;
        double s = 0.0;
        for (int d = 0; d < 96; d++) s += (double)cp[d] * (double)cp[d];
        cnorm[k] = (float)s;
    }
}

__device__ __forceinline__ float gelu_tanh(float v) {
    float u = 0.7978845608028654f * (v + 0.044715f * v * v * v);
    return 0.5f * v * (1.f + tanhf(u));
}

// ---------------- layer 1 fused: conv + gelu + 1x1 + GLU ----------------
// launch_bounds(256,2): budget ~256 VGPR -> g[48]+z[96] stay in registers.
// Works because g/z are ACCUMULATORS (written every iter -> not
// rematerializable, not cheaply spillable).
__global__ __launch_bounds__(256, 2) void henc1_kernel(
    const float* __restrict__ x, const float* __restrict__ w1t,
    const float* __restrict__ b1, const float* __restrict__ w2t,
    const float* __restrict__ b2, float* __restrict__ y1)
{
    __shared__ float gs[48 * 256];
    int bh = blockIdx.x;           // b*512 + ho
    int ho = bh & 511, b = bh >> 9;
    int t = threadIdx.x;

    float g[48];
#pragma unroll
    for (int oc = 0; oc < 48; oc++) g[oc] = b1[oc];

    const float* xb = x + (size_t)b * 2 * H1IN * TT;
    int hbase = ho * 4 - 2;
    for (int ci = 0; ci < 2; ci++) {
        for (int kh = 0; kh < 8; kh++) {
            int hi = hbase + kh;
            float v = (hi >= 0 && hi < H1IN) ? xb[((size_t)ci * H1IN + hi) * TT + t] : 0.f;
            const float* wp = w1t + (ci * 8 + kh) * 48;
#pragma unroll
            for (int oc = 0; oc < 48; oc++) g[oc] = fmaf(v, wp[oc], g[oc]);
        }
    }
#pragma unroll
    for (int oc = 0; oc < 48; oc++) gs[oc * 256 + t] = gelu_tanh(g[oc]);

    float z[96];
#pragma unroll
    for (int oc = 0; oc < 96; oc++) z[oc] = b2[oc];
    for (int c = 0; c < 48; c++) {
        float v = gs[c * 256 + t];
        const float* wp = w2t + c * 96;
#pragma unroll
        for (int oc = 0; oc < 96; oc++) z[oc] = fmaf(v, wp[oc], z[oc]);
    }

    float* yb = y1 + (size_t)b * 48 * H1OUT * TT + (size_t)ho * TT + t;
#pragma unroll
    for (int co = 0; co < 48; co++) {
        float o = z[co] / (1.f + expf(-z[co + 48]));   // a * sigmoid(b)
        yb[(size_t)co * H1OUT * TT] = o;
    }
}

// ---------------- layer 2 conv + gelu ----------------
__global__ __launch_bounds__(256, 2) void conv2a_kernel(
    const float* __restrict__ y1, const float* __restrict__ w3t,
    const float* __restrict__ b3, float* __restrict__ g2)
{
    int bh = blockIdx.x;           // b*128 + ho
    int ho = bh & 127, b = bh >> 7;
    int t = threadIdx.x;

    float g[96];
#pragma unroll
    for (int oc = 0; oc < 96; oc++) g[oc] = b3[oc];

    const float* xb = y1 + (size_t)b * 48 * H2IN * TT;
    int hbase = ho * 4 - 2;
    for (int kh = 0; kh < 8; kh++) {
        int hi = hbase + kh;
        if (hi < 0 || hi >= H2IN) continue;       // wave-uniform branch
        const float* xr = xb + (size_t)hi * TT + t;
        for (int ci = 0; ci < 48; ci++) {
            float v = xr[(size_t)ci * H2IN * TT];
            const float* wp = w3t + (ci * 8 + kh) * 96;
#pragma unroll
            for (int oc = 0; oc < 96; oc++) g[oc] = fmaf(v, wp[oc], g[oc]);
        }
    }

    float* gp = g2 + (size_t)b * 96 * NPTS + (size_t)ho * TT + t;
#pragma unroll
    for (int oc = 0; oc < 96; oc++) gp[(size_t)oc * NPTS] = gelu_tanh(g[oc]);
}

// ---------------- layer 2 rewrite (1x1 -> 192) + GLU ----------------
__global__ __launch_bounds__(256, 2) void rw2b_kernel(
    const float* __restrict__ g2, const float* __restrict__ w4t,
    const float* __restrict__ b4, float* __restrict__ outv)
{
    int i = blockIdx.x * 256 + threadIdx.x;   // 0 .. 262143
    int b = i >> 15, p = i & 32767;
    const float* gp = g2 + (size_t)b * 96 * NPTS + p;
    float* op = outv + (size_t)b * 96 * NPTS + p;

    for (int half = 0; half < 2; half++) {
        float za[48], zb[48];
#pragma unroll
        for (int j = 0; j < 48; j++) {
            za[j] = b4[half * 48 + j];
            zb[j] = b4[96 + half * 48 + j];
        }
        for (int c = 0; c < 96; c++) {
            float v = gp[(size_t)c * NPTS];
            const float* wp = w4t + c * 192;
#pragma unroll
            for (int j = 0; j < 48; j++) {
                za[j] = fmaf(v, wp[half * 48 + j], za[j]);
                zb[j] = fmaf(v, wp[96 + half * 48 + j], zb[j]);
            }
        }
#pragma unroll
        for (int j = 0; j < 48; j++) {
            float o = za[j] / (1.f + expf(-zb[j]));
            op[(size_t)(half * 48 + j) * NPTS] = o;
        }
    }
}

// ---------------- VQ: distances, argmin, gather ----------------
// R6: third submission of the R4-derived LDS design (R5/R6 benches died as
// "container failed twice" with no compile/pytest evidence -> diagnosed as
// broker outage, not source; full bounds/hang audit in journal).
// Design recap: R4 was numerically correct and fixed the R3 HBM re-fetch
// (FETCH 1.6GB -> 56MB) but ran at 1 block/CU (49.6KB LDS + VGPR=188,
// 12% occ, VALUBusy 25%, 4255us). This version removes the occupancy
// killers:
//  - 4 threads/point (24 dims each), 64 points/block -> LDS 64*97*4=24.8KB
//  - smaller per-thread live set (<=6 f-quads + acc[32]) -> VGPR <=128
//  - #pragma unroll 1 on the k0 loop (768 FMAs/iter already; unrolling
//    only re-inflates VGPR)
//  - quad combine: 2-step shfl_xor butterfly; all 4 lanes end with
//    bit-identical dots -> identical argmin state, divergence-free gather
// LDS pad 97 (97%32==1): stage writes and in-loop reads 2-way bank
// aliased = free on wave64 (m136).
// Fallback pre-commit: another container error -> revert vq to R0 variant
// to re-establish measurement, then re-introduce this as a delta.
__global__ __launch_bounds__(256, 4) void vq_kernel(
    const float* __restrict__ bq, const float* __restrict__ cb,
    const float* __restrict__ cnorm,
    float* __restrict__ latent, float* __restrict__ idxf)
{
    __shared__ float fs[64 * 97];
    int tid = threadIdx.x;
    int gp0 = blockIdx.x * 64;           // 4096 blocks; 512 blocks/batch -> no straddle
    int b = gp0 >> 15, p0 = gp0 & 32767;
    const float* fb = bq + (size_t)b * 96 * NPTS;

    // ---- stage f-tile: 96 channels x 64 points, coalesced (24 iters) ----
    {
        int pl = tid & 63, c0 = tid >> 6;         // wave-uniform c within a wave
        const float* src = fb + p0 + pl;
#pragma unroll 6
        for (int i = 0; i < 24; i++) {
            int c = c0 + 4 * i;
            fs[pl * 97 + c] = src[(size_t)c * NPTS];
        }
    }
    __syncthreads();

    int pt = tid >> 2, h = tid & 3;               // point-in-tile, dim-quarter
    const float* fl = fs + pt * 97 + h * 24;

    float best = 3.402823466e+38f, best2 = 3.402823466e+38f;
    int bi = 0, bi2 = 0;

#pragma unroll 1
    for (int k0 = 0; k0 < 1024; k0 += 32) {
        float acc[32];
#pragma unroll
        for (int j = 0; j < 32; j++) acc[j] = 0.f;

        const float* cbase = cb + (size_t)k0 * 96 + h * 24;
#pragma unroll
        for (int dq = 0; dq < 6; dq++) {          // 24 dims / 4
            float f0 = fl[4 * dq + 0];
            float f1 = fl[4 * dq + 1];
            float f2 = fl[4 * dq + 2];
            float f3 = fl[4 * dq + 3];
            const float* cq = cbase + 4 * dq;
#pragma unroll
            for (int j = 0; j < 32; j++) {
                acc[j] = fmaf(f0, cq[j * 96 + 0], acc[j]);
                acc[j] = fmaf(f1, cq[j * 96 + 1], acc[j]);
                acc[j] = fmaf(f2, cq[j * 96 + 2], acc[j]);
                acc[j] = fmaf(f3, cq[j * 96 + 3], acc[j]);
            }
        }

#pragma unroll
        for (int j = 0; j < 32; j++) {
            float o1 = __shfl_xor(acc[j], 1);     // partner quarter (h^1)
            float a  = acc[j] + o1;
            float o2 = __shfl_xor(a, 2);          // partner pair (h^2)
            float dot = a + o2;                   // bit-identical in all 4 lanes
            float s = fmaf(-2.f, dot, cnorm[k0 + j]);
            if (s < best) {                       // strict < -> first-min tie-break
                best2 = best; bi2 = bi;
                best = s;     bi = k0 + j;
            } else if (s < best2) {
                best2 = s;    bi2 = k0 + j;
            }
        }
    }

    // near-tie rescue: fp64 rescore (cold; all 4 lanes identical -> quad
    // keeps an identical bi)
    const float* fpt = fb + p0 + pt;
    if (best2 - best < 1e-3f * fmaxf(1.0f, fabsf(best))) {
        const float* c1 = cb + (size_t)bi  * 96;
        const float* c2 = cb + (size_t)bi2 * 96;
        double s1 = 0.0, s2 = 0.0;
        for (int d = 0; d < 96; d++) {
            double fd = (double)fpt[(size_t)d * NPTS];
            double x1 = (double)c1[d], x2 = (double)c2[d];
            s1 += x1 * (x1 - 2.0 * fd);
            s2 += x2 * (x2 - 2.0 * fd);
        }
        if (s2 < s1 || (s2 == s1 && bi2 < bi)) bi = bi2;
    }

    if (h == 0) idxf[gp0 + pt] = (float)bi;
    const float* cbest = cb + (size_t)bi * 96 + h * 24;
    float* lp = latent + (size_t)b * 96 * NPTS + p0 + pt;
#pragma unroll
    for (int j = 0; j < 24; j++) {
        lp[(size_t)(h * 24 + j) * NPTS] = cbest[j];
    }
}

extern "C" void kernel_launch(void* const* d_in, const int* in_sizes, int n_in,
                              void* d_out, int out_size, void* d_ws, size_t ws_size,
                              hipStream_t stream) {
    const float* x  = (const float*)d_in[0];
    const float* w1 = (const float*)d_in[1];
    const float* b1 = (const float*)d_in[2];
    const float* w2 = (const float*)d_in[3];
    const float* b2 = (const float*)d_in[4];
    const float* w3 = (const float*)d_in[5];
    const float* b3 = (const float*)d_in[6];
    const float* w4 = (const float*)d_in[7];
    const float* b4 = (const float*)d_in[8];
    const float* cb = (const float*)d_in[9];

    float* ws    = (float*)d_ws;
    float* y1    = ws;                       // 50331648 floats (201 MB)
    float* w1t   = ws + 50331648;            // 768
    float* w2t   = w1t + 768;                // 4608
    float* w3t   = w2t + 4608;               // 36864
    float* w4t   = w3t + 36864;              // 18432
    float* cnorm = w4t + 18432;              // 1024

    float* out    = (float*)d_out;
    float* latent = out;
    float* idxf   = out + LAT_ELEMS;
    float* bq     = out + LAT_ELEMS + IDX_ELEMS;
    float* g2     = latent;   // latent region is dead until vq_kernel; reuse as conv2 scratch

    prep_kernel<<<241, 256, 0, stream>>>(w1, w2, w3, w4, cb, w1t, w2t, w3t, w4t, cnorm);
    henc1_kernel<<<8 * 512, 256, 0, stream>>>(x, w1t, b1, w2t, b2, y1);
    conv2a_kernel<<<8 * 128, 256, 0, stream>>>(y1, w3t, b3, g2);
    rw2b_kernel<<<1024, 256, 0, stream>>>(g2, w4t, b4, bq);
    vq_kernel<<<4096, 256, 0, stream>>>(bq, cb, cnorm, latent, idxf);
}

// Round 8
// 15336.107 us; speedup vs baseline: 2.6573x; 2.6573x over previous
//
#include <hip/hip_runtime.h>
#include <math.h>

// Shapes:
// x:  [8, 2, 2048, 256]
// L1: conv k(8,1) s(4,1) p(2,0): -> [8,48,512,256]; gelu; 1x1 ->96; GLU -> [8,48,512,256]  (y1, ws)
// L2: conv -> [8,96,128,256]; gelu (g2, staged in d_out latent region); 1x1 ->192; GLU -> beforvq (d_out)
// VQ: argmin over 1024 codes of ||f - c||^2, latent = codebook[idx]
//
// d_out layout (fp32): latent [25165824] | indices-as-float [262144] | beforvq [25165824]

#define H1IN 2048
#define H1OUT 512
#define H2IN 512
#define H2OUT 128
#define TT 256
#define NPTS 32768           // 128*256 per batch
#define LAT_ELEMS 25165824   // 8*96*128*256
#define IDX_ELEMS 262144

// ---------------- prep: transpose weights, codebook norms ----------------
__global__ __launch_bounds__(256) void prep_kernel(
    const float* __restrict__ w1, const float* __restrict__ w2,
    const float* __restrict__ w3, const float* __restrict__ w4,
    const float* __restrict__ cb,
    float* __restrict__ w1t, float* __restrict__ w2t,
    float* __restrict__ w3t, float* __restrict__ w4t,
    float* __restrict__ cnorm)
{
    int i = blockIdx.x * 256 + threadIdx.x;
    if (i < 768) {                       // w1t[(ci*8+kh)*48+oc] = w1[(oc*2+ci)*8+kh]
        int oc = i % 48; int r = i / 48;
        w1t[i] = w1[(oc * 2 + (r >> 3)) * 8 + (r & 7)];
    } else if (i < 5376) {               // w2t[c*96+oc] = w2[oc*48+c]
        int j = i - 768;
        int oc = j % 96, c = j / 96;
        w2t[j] = w2[oc * 48 + c];
    } else if (i < 42240) {              // w3t[(ci*8+kh)*96+oc] = w3[(oc*48+ci)*8+kh]
        int j = i - 5376;
        int oc = j % 96; int r = j / 96;
        w3t[j] = w3[(oc * 48 + (r >> 3)) * 8 + (r & 7)];
    } else if (i < 60672) {              // w4t[c*192+oc] = w4[oc*96+c]
        int j = i - 42240;
        int oc = j % 192, c = j / 192;
        w4t[j] = w4[oc * 96 + c];
    } else if (i < 61696) {              // cnorm[k] = sum_d cb[k][d]^2 (fp64 accumulate)
        int k = i - 60672;
        const float* cp = cb + (size_t)k * 96;
        double s = 0.0;
        for (int d = 0; d < 96; d++) s += (double)cp[d] * (double)cp[d];
        cnorm[k] = (float)s;
    }
}

__device__ __forceinline__ float gelu_tanh(float v) {
    float u = 0.7978845608028654f * (v + 0.044715f * v * v * v);
    return 0.5f * v * (1.f + tanhf(u));
}

// ---------------- layer 1 fused: conv + gelu + 1x1 + GLU ----------------
// launch_bounds(256,2): budget ~256 VGPR -> g[48]+z[96] stay in registers.
// Works because g/z are ACCUMULATORS and the weight loads are WAVE-UNIFORM
// (scalar s_load, zero VGPR pressure). This {accumulator + scalar operand +
// one streamed vector value} shape is the ONLY shape this backend compiles
// at high VGPR without spill (see vq history R0-R7).
__global__ __launch_bounds__(256, 2) void henc1_kernel(
    const float* __restrict__ x, const float* __restrict__ w1t,
    const float* __restrict__ b1, const float* __restrict__ w2t,
    const float* __restrict__ b2, float* __restrict__ y1)
{
    __shared__ float gs[48 * 256];
    int bh = blockIdx.x;           // b*512 + ho
    int ho = bh & 511, b = bh >> 9;
    int t = threadIdx.x;

    float g[48];
#pragma unroll
    for (int oc = 0; oc < 48; oc++) g[oc] = b1[oc];

    const float* xb = x + (size_t)b * 2 * H1IN * TT;
    int hbase = ho * 4 - 2;
    for (int ci = 0; ci < 2; ci++) {
        for (int kh = 0; kh < 8; kh++) {
            int hi = hbase + kh;
            float v = (hi >= 0 && hi < H1IN) ? xb[((size_t)ci * H1IN + hi) * TT + t] : 0.f;
            const float* wp = w1t + (ci * 8 + kh) * 48;
#pragma unroll
            for (int oc = 0; oc < 48; oc++) g[oc] = fmaf(v, wp[oc], g[oc]);
        }
    }
#pragma unroll
    for (int oc = 0; oc < 48; oc++) gs[oc * 256 + t] = gelu_tanh(g[oc]);

    float z[96];
#pragma unroll
    for (int oc = 0; oc < 96; oc++) z[oc] = b2[oc];
    for (int c = 0; c < 48; c++) {
        float v = gs[c * 256 + t];
        const float* wp = w2t + c * 96;
#pragma unroll
        for (int oc = 0; oc < 96; oc++) z[oc] = fmaf(v, wp[oc], z[oc]);
    }

    float* yb = y1 + (size_t)b * 48 * H1OUT * TT + (size_t)ho * TT + t;
#pragma unroll
    for (int co = 0; co < 48; co++) {
        float o = z[co] / (1.f + expf(-z[co + 48]));   // a * sigmoid(b)
        yb[(size_t)co * H1OUT * TT] = o;
    }
}

// ---------------- layer 2 conv + gelu ----------------
__global__ __launch_bounds__(256, 2) void conv2a_kernel(
    const float* __restrict__ y1, const float* __restrict__ w3t,
    const float* __restrict__ b3, float* __restrict__ g2)
{
    int bh = blockIdx.x;           // b*128 + ho
    int ho = bh & 127, b = bh >> 7;
    int t = threadIdx.x;

    float g[96];
#pragma unroll
    for (int oc = 0; oc < 96; oc++) g[oc] = b3[oc];

    const float* xb = y1 + (size_t)b * 48 * H2IN * TT;
    int hbase = ho * 4 - 2;
    for (int kh = 0; kh < 8; kh++) {
        int hi = hbase + kh;
        if (hi < 0 || hi >= H2IN) continue;       // wave-uniform branch
        const float* xr = xb + (size_t)hi * TT + t;
        for (int ci = 0; ci < 48; ci++) {
            float v = xr[(size_t)ci * H2IN * TT];
            const float* wp = w3t + (ci * 8 + kh) * 96;
#pragma unroll
            for (int oc = 0; oc < 96; oc++) g[oc] = fmaf(v, wp[oc], g[oc]);
        }
    }

    float* gp = g2 + (size_t)b * 96 * NPTS + (size_t)ho * TT + t;
#pragma unroll
    for (int oc = 0; oc < 96; oc++) gp[(size_t)oc * NPTS] = gelu_tanh(g[oc]);
}

// ---------------- layer 2 rewrite (1x1 -> 192) + GLU ----------------
__global__ __launch_bounds__(256, 2) void rw2b_kernel(
    const float* __restrict__ g2, const float* __restrict__ w4t,
    const float* __restrict__ b4, float* __restrict__ outv)
{
    int i = blockIdx.x * 256 + threadIdx.x;   // 0 .. 262143
    int b = i >> 15, p = i & 32767;
    const float* gp = g2 + (size_t)b * 96 * NPTS + p;
    float* op = outv + (size_t)b * 96 * NPTS + p;

    for (int half = 0; half < 2; half++) {
        float za[48], zb[48];
#pragma unroll
        for (int j = 0; j < 48; j++) {
            za[j] = b4[half * 48 + j];
            zb[j] = b4[96 + half * 48 + j];
        }
        for (int c = 0; c < 96; c++) {
            float v = gp[(size_t)c * NPTS];
            const float* wp = w4t + c * 192;
#pragma unroll
            for (int j = 0; j < 48; j++) {
                za[j] = fmaf(v, wp[half * 48 + j], za[j]);
                zb[j] = fmaf(v, wp[96 + half * 48 + j], zb[j]);
            }
        }
#pragma unroll
        for (int j = 0; j < 48; j++) {
            float o = za[j] / (1.f + expf(-zb[j]));
            op[(size_t)(half * 48 + j) * NPTS] = o;
        }
    }
}

// ---------------- VQ: distances, argmin, gather ----------------
// R8. Diagnosis history:
//  R0-R2: read-only f[96] never stays in VGPRs (remat / remat / forced spill).
//  R3: thread=point, acc[32], WAVE-UNIFORM codebook loads (scalar s_load) ->
//      compiled perfectly (VGPR 44, VALU 73%) but f re-read 32x from global
//      -> 1.6GB HBM, 2.3ms.
//  R4/R7: f in LDS fixed the fetch (56MB) but split dims across lanes ->
//      codebook pointer became LANE-DIVERGENT -> vector loads -> hoisting
//      pressure -> backend (stuck at ~64 VGPR) spilled acc[32] to scratch:
//      R7 = 88GB scratch writes, VALUBusy 2.7%, 40ms.
// Rule: only {accumulators + scalar codebook + streamed f} compiles clean.
// R8 keeps thread=point (scalar codebook, exact R3 inner loop) AND f in LDS,
// recovering occupancy by splitting the K-RANGE across the 4 waves of the
// block instead of splitting dims across lanes:
//   block = 256 thr = 64 points x 4 k-quarters; quarter = tid>>6 is
//   WAVE-uniform -> codebook loads stay scalar. LDS = 64pt x 96ch x 4B
//   = 24.6KB + 4KB merge buf -> 5 blocks/CU = 20 waves/CU = 5 waves/SIMD.
// Each (point, quarter) scans 256 codes (8 k-tiles of 32) with acc[32];
// per-quarter top-2 merged via LDS with explicit (s,k) tie-break ->
// reproduces global first-min argmin; fp64 near-tie rescue unchanged;
// gather split 24 ch/thread.
// fs layout [c][pt] stride 64: lanes read/write consecutive dwords -> 2
// lanes/bank on wave64 = conflict-free (m136).
__global__ __launch_bounds__(256, 4) void vq_kernel(
    const float* __restrict__ bq, const float* __restrict__ cb,
    const float* __restrict__ cnorm,
    float* __restrict__ latent, float* __restrict__ idxf)
{
    __shared__ float fs[96 * 64];        // [c][pt]
    __shared__ float mb[4][64][4];       // per-wave {best, bi, best2, bi2}
    int tid = threadIdx.x;
    int pl = tid & 63, w = tid >> 6;     // point lane, wave id (= k-quarter)
    int gp0 = blockIdx.x * 64;           // 4096 blocks; 512/batch -> no straddle
    int b = gp0 >> 15, p0 = gp0 & 32767;
    const float* fb = bq + (size_t)b * 96 * NPTS;

    // ---- stage f-tile: 96 channels x 64 points, coalesced ----
    {
        const float* src = fb + p0 + pl;
#pragma unroll 6
        for (int i = 0; i < 24; i++) {
            int c = w * 24 + i;
            fs[c * 64 + pl] = src[(size_t)c * NPTS];
        }
    }
    __syncthreads();

    const float* fl = fs + pl;           // read fl[d*64]

    float best = 3.402823466e+38f, best2 = 3.402823466e+38f;
    int bi = 0, bi2 = 0;
    int kbase = w * 256;                 // this wave's k-quarter

#pragma unroll 1
    for (int kt = 0; kt < 8; kt++) {
        int k0 = kbase + kt * 32;
        float acc[32];
#pragma unroll
        for (int j = 0; j < 32; j++) acc[j] = 0.f;

        const float* cbase = cb + (size_t)k0 * 96;   // wave-uniform -> s_load
#pragma unroll 4
        for (int dq = 0; dq < 24; dq++) {
            float f0 = fl[(4 * dq + 0) * 64];
            float f1 = fl[(4 * dq + 1) * 64];
            float f2 = fl[(4 * dq + 2) * 64];
            float f3 = fl[(4 * dq + 3) * 64];
            const float* cq = cbase + dq * 4;
#pragma unroll
            for (int j = 0; j < 32; j++) {
                acc[j] = fmaf(f0, cq[j * 96 + 0], acc[j]);
                acc[j] = fmaf(f1, cq[j * 96 + 1], acc[j]);
                acc[j] = fmaf(f2, cq[j * 96 + 2], acc[j]);
                acc[j] = fmaf(f3, cq[j * 96 + 3], acc[j]);
            }
        }

#pragma unroll
        for (int j = 0; j < 32; j++) {
            float s = fmaf(-2.f, acc[j], cnorm[k0 + j]);
            if (s < best) {                       // strict < -> first-min within quarter
                best2 = best; bi2 = bi;
                best = s;     bi = k0 + j;
            } else if (s < best2) {
                best2 = s;    bi2 = k0 + j;
            }
        }
    }

    // ---- publish per-quarter top-2, merge across the 4 waves ----
    mb[w][pl][0] = best;  mb[w][pl][1] = (float)bi;   // k<=1023 exact in fp32
    mb[w][pl][2] = best2; mb[w][pl][3] = (float)bi2;
    __syncthreads();

    float bs = 3.402823466e+38f, b2 = 3.402823466e+38f;
    int ib = 0, i2 = 0;
#pragma unroll
    for (int ww = 0; ww < 4; ww++) {
#pragma unroll
        for (int pr = 0; pr < 2; pr++) {
            float s = mb[ww][pl][2 * pr];
            int  k = (int)mb[ww][pl][2 * pr + 1];
            if (s < bs || (s == bs && k < ib)) {  // global first-min tie-break
                b2 = bs; i2 = ib; bs = s; ib = k;
            } else if (s < b2 || (s == b2 && k < i2)) {
                b2 = s;  i2 = k;
            }
        }
    }

    // near-tie rescue: fp64 rescore (cold; all 4 threads of a point compute
    // identically from identical merged state -> identical final ib)
    const float* fpt = fb + p0 + pl;
    if (b2 - bs < 1e-3f * fmaxf(1.0f, fabsf(bs))) {
        const float* c1 = cb + (size_t)ib * 96;
        const float* c2 = cb + (size_t)i2 * 96;
        double s1 = 0.0, s2 = 0.0;
        for (int d = 0; d < 96; d++) {
            double fd = (double)fpt[(size_t)d * NPTS];
            double x1 = (double)c1[d], x2 = (double)c2[d];
            s1 += x1 * (x1 - 2.0 * fd);
            s2 += x2 * (x2 - 2.0 * fd);
        }
        if (s2 < s1 || (s2 == s1 && i2 < ib)) ib = i2;
    }

    if (w == 0) idxf[gp0 + pl] = (float)ib;
    const float* cbest = cb + (size_t)ib * 96 + w * 24;
    float* lp = latent + (size_t)b * 96 * NPTS + p0 + pl;
#pragma unroll
    for (int j = 0; j < 24; j++) {
        lp[(size_t)(w * 24 + j) * NPTS] = cbest[j];
    }
}

extern "C" void kernel_launch(void* const* d_in, const int* in_sizes, int n_in,
                              void* d_out, int out_size, void* d_ws, size_t ws_size,
                              hipStream_t stream) {
    const float* x  = (const float*)d_in[0];
    const float* w1 = (const float*)d_in[1];
    const float* b1 = (const float*)d_in[2];
    const float* w2 = (const float*)d_in[3];
    const float* b2 = (const float*)d_in[4];
    const float* w3 = (const float*)d_in[5];
    const float* b3 = (const float*)d_in[6];
    const float* w4 = (const float*)d_in[7];
    const float* b4 = (const float*)d_in[8];
    const float* cb = (const float*)d_in[9];

    float* ws    = (float*)d_ws;
    float* y1    = ws;                       // 50331648 floats (201 MB)
    float* w1t   = ws + 50331648;            // 768
    float* w2t   = w1t + 768;                // 4608
    float* w3t   = w2t + 4608;               // 36864
    float* w4t   = w3t + 36864;              // 18432
    float* cnorm = w4t + 18432;              // 1024

    float* out    = (float*)d_out;
    float* latent = out;
    float* idxf   = out + LAT_ELEMS;
    float* bq     = out + LAT_ELEMS + IDX_ELEMS;
    float* g2     = latent;   // latent region is dead until vq_kernel; reuse as conv2 scratch

    prep_kernel<<<241, 256, 0, stream>>>(w1, w2, w3, w4, cb, w1t, w2t, w3t, w4t, cnorm);
    henc1_kernel<<<8 * 512, 256, 0, stream>>>(x, w1t, b1, w2t, b2, y1);
    conv2a_kernel<<<8 * 128, 256, 0, stream>>>(y1, w3t, b3, g2);
    rw2b_kernel<<<1024, 256, 0, stream>>>(g2, w4t, b4, bq);
    vq_kernel<<<4096, 256, 0, stream>>>(bq, cb, cnorm, latent, idxf);
}

// Round 9
// 2767.750 us; speedup vs baseline: 14.7244x; 5.5410x over previous
//
#include <hip/hip_runtime.h>
#include <math.h>

// Shapes:
// x:  [8, 2, 2048, 256]
// L1: conv k(8,1) s(4,1) p(2,0): -> [8,48,512,256]; gelu; 1x1 ->96; GLU -> [8,48,512,256]  (y1, ws)
// L2: conv -> [8,96,128,256]; gelu (g2, staged in d_out latent region); 1x1 ->192; GLU -> beforvq (d_out)
// VQ: argmin over 1024 codes of ||f - c||^2, latent = codebook[idx]
//
// d_out layout (fp32): latent [25165824] | indices-as-float [262144] | beforvq [25165824]

#define H1IN 2048
#define H1OUT 512
#define H2IN 512
#define H2OUT 128
#define TT 256
#define NPTS 32768           // 128*256 per batch
#define LAT_ELEMS 25165824   // 8*96*128*256
#define IDX_ELEMS 262144

// ---------------- prep: transpose weights, codebook norms ----------------
__global__ __launch_bounds__(256) void prep_kernel(
    const float* __restrict__ w1, const float* __restrict__ w2,
    const float* __restrict__ w3, const float* __restrict__ w4,
    const float* __restrict__ cb,
    float* __restrict__ w1t, float* __restrict__ w2t,
    float* __restrict__ w3t, float* __restrict__ w4t,
    float* __restrict__ cnorm)
{
    int i = blockIdx.x * 256 + threadIdx.x;
    if (i < 768) {                       // w1t[(ci*8+kh)*48+oc] = w1[(oc*2+ci)*8+kh]
        int oc = i % 48; int r = i / 48;
        w1t[i] = w1[(oc * 2 + (r >> 3)) * 8 + (r & 7)];
    } else if (i < 5376) {               // w2t[c*96+oc] = w2[oc*48+c]
        int j = i - 768;
        int oc = j % 96, c = j / 96;
        w2t[j] = w2[oc * 48 + c];
    } else if (i < 42240) {              // w3t[(ci*8+kh)*96+oc] = w3[(oc*48+ci)*8+kh]
        int j = i - 5376;
        int oc = j % 96; int r = j / 96;
        w3t[j] = w3[(oc * 48 + (r >> 3)) * 8 + (r & 7)];
    } else if (i < 60672) {              // w4t[c*192+oc] = w4[oc*96+c]
        int j = i - 42240;
        int oc = j % 192, c = j / 192;
        w4t[j] = w4[oc * 96 + c];
    } else if (i < 61696) {              // cnorm[k] = sum_d cb[k][d]^2 (fp64 accumulate)
        int k = i - 60672;
        const float* cp = cb + (size_t)k * 96;
        double s = 0.0;
        for (int d = 0; d < 96; d++) s += (double)cp[d] * (double)cp[d];
        cnorm[k] = (float)s;
    }
}

__device__ __forceinline__ float gelu_tanh(float v) {
    float u = 0.7978845608028654f * (v + 0.044715f * v * v * v);
    return 0.5f * v * (1.f + tanhf(u));
}

// ---------------- layer 1 fused: conv + gelu + 1x1 + GLU ----------------
// launch_bounds(256,2): budget ~256 VGPR -> g[48]+z[96] stay in registers.
// Works because g/z are ACCUMULATORS and the weight loads are PROVABLY
// UNIFORM (derived from loop induction vars -> scalar s_load, zero VGPR
// pressure). {accumulator + scalar operand + streamed vector value} is the
// only shape this backend compiles at high VGPR without spill (vq R0-R8).
__global__ __launch_bounds__(256, 2) void henc1_kernel(
    const float* __restrict__ x, const float* __restrict__ w1t,
    const float* __restrict__ b1, const float* __restrict__ w2t,
    const float* __restrict__ b2, float* __restrict__ y1)
{
    __shared__ float gs[48 * 256];
    int bh = blockIdx.x;           // b*512 + ho
    int ho = bh & 511, b = bh >> 9;
    int t = threadIdx.x;

    float g[48];
#pragma unroll
    for (int oc = 0; oc < 48; oc++) g[oc] = b1[oc];

    const float* xb = x + (size_t)b * 2 * H1IN * TT;
    int hbase = ho * 4 - 2;
    for (int ci = 0; ci < 2; ci++) {
        for (int kh = 0; kh < 8; kh++) {
            int hi = hbase + kh;
            float v = (hi >= 0 && hi < H1IN) ? xb[((size_t)ci * H1IN + hi) * TT + t] : 0.f;
            const float* wp = w1t + (ci * 8 + kh) * 48;
#pragma unroll
            for (int oc = 0; oc < 48; oc++) g[oc] = fmaf(v, wp[oc], g[oc]);
        }
    }
#pragma unroll
    for (int oc = 0; oc < 48; oc++) gs[oc * 256 + t] = gelu_tanh(g[oc]);

    float z[96];
#pragma unroll
    for (int oc = 0; oc < 96; oc++) z[oc] = b2[oc];
    for (int c = 0; c < 48; c++) {
        float v = gs[c * 256 + t];
        const float* wp = w2t + c * 96;
#pragma unroll
        for (int oc = 0; oc < 96; oc++) z[oc] = fmaf(v, wp[oc], z[oc]);
    }

    float* yb = y1 + (size_t)b * 48 * H1OUT * TT + (size_t)ho * TT + t;
#pragma unroll
    for (int co = 0; co < 48; co++) {
        float o = z[co] / (1.f + expf(-z[co + 48]));   // a * sigmoid(b)
        yb[(size_t)co * H1OUT * TT] = o;
    }
}

// ---------------- layer 2 conv + gelu ----------------
__global__ __launch_bounds__(256, 2) void conv2a_kernel(
    const float* __restrict__ y1, const float* __restrict__ w3t,
    const float* __restrict__ b3, float* __restrict__ g2)
{
    int bh = blockIdx.x;           // b*128 + ho
    int ho = bh & 127, b = bh >> 7;
    int t = threadIdx.x;

    float g[96];
#pragma unroll
    for (int oc = 0; oc < 96; oc++) g[oc] = b3[oc];

    const float* xb = y1 + (size_t)b * 48 * H2IN * TT;
    int hbase = ho * 4 - 2;
    for (int kh = 0; kh < 8; kh++) {
        int hi = hbase + kh;
        if (hi < 0 || hi >= H2IN) continue;       // wave-uniform branch
        const float* xr = xb + (size_t)hi * TT + t;
        for (int ci = 0; ci < 48; ci++) {
            float v = xr[(size_t)ci * H2IN * TT];
            const float* wp = w3t + (ci * 8 + kh) * 96;
#pragma unroll
            for (int oc = 0; oc < 96; oc++) g[oc] = fmaf(v, wp[oc], g[oc]);
        }
    }

    float* gp = g2 + (size_t)b * 96 * NPTS + (size_t)ho * TT + t;
#pragma unroll
    for (int oc = 0; oc < 96; oc++) gp[(size_t)oc * NPTS] = gelu_tanh(g[oc]);
}

// ---------------- layer 2 rewrite (1x1 -> 192) + GLU ----------------
__global__ __launch_bounds__(256, 2) void rw2b_kernel(
    const float* __restrict__ g2, const float* __restrict__ w4t,
    const float* __restrict__ b4, float* __restrict__ outv)
{
    int i = blockIdx.x * 256 + threadIdx.x;   // 0 .. 262143
    int b = i >> 15, p = i & 32767;
    const float* gp = g2 + (size_t)b * 96 * NPTS + p;
    float* op = outv + (size_t)b * 96 * NPTS + p;

    for (int half = 0; half < 2; half++) {
        float za[48], zb[48];
#pragma unroll
        for (int j = 0; j < 48; j++) {
            za[j] = b4[half * 48 + j];
            zb[j] = b4[96 + half * 48 + j];
        }
        for (int c = 0; c < 96; c++) {
            float v = gp[(size_t)c * NPTS];
            const float* wp = w4t + c * 192;
#pragma unroll
            for (int j = 0; j < 48; j++) {
                za[j] = fmaf(v, wp[half * 48 + j], za[j]);
                zb[j] = fmaf(v, wp[96 + half * 48 + j], zb[j]);
            }
        }
#pragma unroll
        for (int j = 0; j < 48; j++) {
            float o = za[j] / (1.f + expf(-zb[j]));
            op[(size_t)(half * 48 + j) * NPTS] = o;
        }
    }
}

// ---------------- VQ: distances, argmin, gather ----------------
// R9 = R8 + ONE FIX: readfirstlane on the wave id.
// R8 diagnosis: kbase = (tid>>6)*256 is wave-uniform IN FACT, but divergence
// analysis marks any f(threadIdx) as DIVERGENT -> codebook loads compiled as
// per-lane vector loads (not s_load) -> hoisting pressure at the backend's
// ~64-VGPR target -> acc[32] spilled to scratch (67GB traffic, VALU 7%,
// 14.8ms). R3 proved the identical inner loop compiles clean (VGPR=44,
// VALU 73%) when k0 derives from a loop induction var (provably uniform ->
// s_load). Fix: __builtin_amdgcn_readfirstlane(w) materializes w in an
// SGPR; kbase/cbase/cnorm-index become provably uniform -> the R3-proven
// {acc[32] + scalar codebook + streamed f} shape, now with f in LDS
// (R8's staging kept: FETCH 56MB, 5 blocks/CU).
// Semantic no-op: all lanes of a wave share w, readfirstlane returns that
// shared value. Merge/rescue/gather unchanged from R8 (which PASSED).
__global__ __launch_bounds__(256, 4) void vq_kernel(
    const float* __restrict__ bq, const float* __restrict__ cb,
    const float* __restrict__ cnorm,
    float* __restrict__ latent, float* __restrict__ idxf)
{
    __shared__ float fs[96 * 64];        // [c][pt]
    __shared__ float mb[4][64][4];       // per-wave {best, bi, best2, bi2}
    int tid = threadIdx.x;
    int pl = tid & 63;
    int w = __builtin_amdgcn_readfirstlane(tid >> 6);  // SGPR: provably uniform
    int gp0 = blockIdx.x * 64;           // 4096 blocks; 512/batch -> no straddle
    int b = gp0 >> 15, p0 = gp0 & 32767;
    const float* fb = bq + (size_t)b * 96 * NPTS;

    // ---- stage f-tile: 96 channels x 64 points, coalesced ----
    {
        const float* src = fb + p0 + pl;
#pragma unroll 6
        for (int i = 0; i < 24; i++) {
            int c = w * 24 + i;
            fs[c * 64 + pl] = src[(size_t)c * NPTS];
        }
    }
    __syncthreads();

    const float* fl = fs + pl;           // read fl[d*64]

    float best = 3.402823466e+38f, best2 = 3.402823466e+38f;
    int bi = 0, bi2 = 0;
    int kbase = w * 256;                 // uniform (w is SGPR)

#pragma unroll 1
    for (int kt = 0; kt < 8; kt++) {
        int k0 = kbase + kt * 32;
        float acc[32];
#pragma unroll
        for (int j = 0; j < 32; j++) acc[j] = 0.f;

        const float* cbase = cb + (size_t)k0 * 96;   // uniform -> s_load
#pragma unroll 4
        for (int dq = 0; dq < 24; dq++) {
            float f0 = fl[(4 * dq + 0) * 64];
            float f1 = fl[(4 * dq + 1) * 64];
            float f2 = fl[(4 * dq + 2) * 64];
            float f3 = fl[(4 * dq + 3) * 64];
            const float* cq = cbase + dq * 4;
#pragma unroll
            for (int j = 0; j < 32; j++) {
                acc[j] = fmaf(f0, cq[j * 96 + 0], acc[j]);
                acc[j] = fmaf(f1, cq[j * 96 + 1], acc[j]);
                acc[j] = fmaf(f2, cq[j * 96 + 2], acc[j]);
                acc[j] = fmaf(f3, cq[j * 96 + 3], acc[j]);
            }
        }

#pragma unroll
        for (int j = 0; j < 32; j++) {
            float s = fmaf(-2.f, acc[j], cnorm[k0 + j]);
            if (s < best) {                       // strict < -> first-min within quarter
                best2 = best; bi2 = bi;
                best = s;     bi = k0 + j;
            } else if (s < best2) {
                best2 = s;    bi2 = k0 + j;
            }
        }
    }

    // ---- publish per-quarter top-2, merge across the 4 waves ----
    mb[w][pl][0] = best;  mb[w][pl][1] = (float)bi;   // k<=1023 exact in fp32
    mb[w][pl][2] = best2; mb[w][pl][3] = (float)bi2;
    __syncthreads();

    float bs = 3.402823466e+38f, b2 = 3.402823466e+38f;
    int ib = 0, i2 = 0;
#pragma unroll
    for (int ww = 0; ww < 4; ww++) {
#pragma unroll
        for (int pr = 0; pr < 2; pr++) {
            float s = mb[ww][pl][2 * pr];
            int  k = (int)mb[ww][pl][2 * pr + 1];
            if (s < bs || (s == bs && k < ib)) {  // global first-min tie-break
                b2 = bs; i2 = ib; bs = s; ib = k;
            } else if (s < b2 || (s == b2 && k < i2)) {
                b2 = s;  i2 = k;
            }
        }
    }

    // near-tie rescue: fp64 rescore (cold; all 4 threads of a point compute
    // identically from identical merged state -> identical final ib)
    const float* fpt = fb + p0 + pl;
    if (b2 - bs < 1e-3f * fmaxf(1.0f, fabsf(bs))) {
        const float* c1 = cb + (size_t)ib * 96;
        const float* c2 = cb + (size_t)i2 * 96;
        double s1 = 0.0, s2 = 0.0;
        for (int d = 0; d < 96; d++) {
            double fd = (double)fpt[(size_t)d * NPTS];
            double x1 = (double)c1[d], x2 = (double)c2[d];
            s1 += x1 * (x1 - 2.0 * fd);
            s2 += x2 * (x2 - 2.0 * fd);
        }
        if (s2 < s1 || (s2 == s1 && i2 < ib)) ib = i2;
    }

    if (w == 0) idxf[gp0 + pl] = (float)ib;
    const float* cbest = cb + (size_t)ib * 96 + w * 24;
    float* lp = latent + (size_t)b * 96 * NPTS + p0 + pl;
#pragma unroll
    for (int j = 0; j < 24; j++) {
        lp[(size_t)(w * 24 + j) * NPTS] = cbest[j];
    }
}

extern "C" void kernel_launch(void* const* d_in, const int* in_sizes, int n_in,
                              void* d_out, int out_size, void* d_ws, size_t ws_size,
                              hipStream_t stream) {
    const float* x  = (const float*)d_in[0];
    const float* w1 = (const float*)d_in[1];
    const float* b1 = (const float*)d_in[2];
    const float* w2 = (const float*)d_in[3];
    const float* b2 = (const float*)d_in[4];
    const float* w3 = (const float*)d_in[5];
    const float* b3 = (const float*)d_in[6];
    const float* w4 = (const float*)d_in[7];
    const float* b4 = (const float*)d_in[8];
    const float* cb = (const float*)d_in[9];

    float* ws    = (float*)d_ws;
    float* y1    = ws;                       // 50331648 floats (201 MB)
    float* w1t   = ws + 50331648;            // 768
    float* w2t   = w1t + 768;                // 4608
    float* w3t   = w2t + 4608;               // 36864
    float* w4t   = w3t + 36864;              // 18432
    float* cnorm = w4t + 18432;              // 1024

    float* out    = (float*)d_out;
    float* latent = out;
    float* idxf   = out + LAT_ELEMS;
    float* bq     = out + LAT_ELEMS + IDX_ELEMS;
    float* g2     = latent;   // latent region is dead until vq_kernel; reuse as conv2 scratch

    prep_kernel<<<241, 256, 0, stream>>>(w1, w2, w3, w4, cb, w1t, w2t, w3t, w4t, cnorm);
    henc1_kernel<<<8 * 512, 256, 0, stream>>>(x, w1t, b1, w2t, b2, y1);
    conv2a_kernel<<<8 * 128, 256, 0, stream>>>(y1, w3t, b3, g2);
    rw2b_kernel<<<1024, 256, 0, stream>>>(g2, w4t, b4, bq);
    vq_kernel<<<4096, 256, 0, stream>>>(bq, cb, cnorm, latent, idxf);
}